// Round 2
// baseline (131.370 us; speedup 1.0000x reference)
//
#include <hip/hip_runtime.h>

#define FXc 384.996f
#define FYc 384.996f
#define CXc 325.85f
#define CYc 237.646f
#define DEPTH_MARGIN 0.003f
#define IMG_H 480
#define IMG_W 640
#define NPIX (IMG_H * IMG_W)

typedef int   i32x4 __attribute__((ext_vector_type(4)));
typedef float f32x4 __attribute__((ext_vector_type(4)));

// ---------- tiny kernel: T = inv(pose_B) @ pose_A ----------
__global__ void compute_T_kernel(const float* __restrict__ poseA,
                                 const float* __restrict__ poseB,
                                 float* __restrict__ T) {
    if (threadIdx.x != 0 || blockIdx.x != 0) return;
    float m[16], inv[16];
#pragma unroll
    for (int i = 0; i < 16; ++i) m[i] = poseB[i];

    inv[0]  =  m[5]*m[10]*m[15] - m[5]*m[11]*m[14] - m[9]*m[6]*m[15] + m[9]*m[7]*m[14] + m[13]*m[6]*m[11] - m[13]*m[7]*m[10];
    inv[4]  = -m[4]*m[10]*m[15] + m[4]*m[11]*m[14] + m[8]*m[6]*m[15] - m[8]*m[7]*m[14] - m[12]*m[6]*m[11] + m[12]*m[7]*m[10];
    inv[8]  =  m[4]*m[9]*m[15]  - m[4]*m[11]*m[13] - m[8]*m[5]*m[15] + m[8]*m[7]*m[13] + m[12]*m[5]*m[11] - m[12]*m[7]*m[9];
    inv[12] = -m[4]*m[9]*m[14]  + m[4]*m[10]*m[13] + m[8]*m[5]*m[14] - m[8]*m[6]*m[13] - m[12]*m[5]*m[10] + m[12]*m[6]*m[9];
    inv[1]  = -m[1]*m[10]*m[15] + m[1]*m[11]*m[14] + m[9]*m[2]*m[15] - m[9]*m[3]*m[14] - m[13]*m[2]*m[11] + m[13]*m[3]*m[10];
    inv[5]  =  m[0]*m[10]*m[15] - m[0]*m[11]*m[14] - m[8]*m[2]*m[15] + m[8]*m[3]*m[14] + m[12]*m[2]*m[11] - m[12]*m[3]*m[10];
    inv[9]  = -m[0]*m[9]*m[15]  + m[0]*m[11]*m[13] + m[8]*m[1]*m[15] - m[8]*m[3]*m[13] - m[12]*m[1]*m[11] + m[12]*m[3]*m[9];
    inv[13] =  m[0]*m[9]*m[14]  - m[0]*m[10]*m[13] - m[8]*m[1]*m[14] + m[8]*m[2]*m[13] + m[12]*m[1]*m[10] - m[12]*m[2]*m[9];
    inv[2]  =  m[1]*m[6]*m[15]  - m[1]*m[7]*m[14]  - m[5]*m[2]*m[15] + m[5]*m[3]*m[14] + m[13]*m[2]*m[7]  - m[13]*m[3]*m[6];
    inv[6]  = -m[0]*m[6]*m[15]  + m[0]*m[7]*m[14]  + m[4]*m[2]*m[15] - m[4]*m[3]*m[14] - m[12]*m[2]*m[7]  + m[12]*m[3]*m[6];
    inv[10] =  m[0]*m[5]*m[15]  - m[0]*m[7]*m[13]  - m[4]*m[1]*m[15] + m[4]*m[3]*m[13] + m[12]*m[1]*m[7]  - m[12]*m[3]*m[5];
    inv[14] = -m[0]*m[5]*m[14]  + m[0]*m[6]*m[13]  + m[4]*m[1]*m[14] - m[4]*m[2]*m[13] - m[12]*m[1]*m[6]  + m[12]*m[2]*m[5];
    inv[3]  = -m[1]*m[6]*m[11]  + m[1]*m[7]*m[10]  + m[5]*m[2]*m[11] - m[5]*m[3]*m[10] - m[9]*m[2]*m[7]   + m[9]*m[3]*m[6];
    inv[7]  =  m[0]*m[6]*m[11]  - m[0]*m[7]*m[10]  - m[4]*m[2]*m[11] + m[4]*m[3]*m[10] + m[8]*m[2]*m[7]   - m[8]*m[3]*m[6];
    inv[11] = -m[0]*m[5]*m[11]  + m[0]*m[7]*m[9]   + m[4]*m[1]*m[11] - m[4]*m[3]*m[9]  - m[8]*m[1]*m[7]   + m[8]*m[3]*m[5];
    inv[15] =  m[0]*m[5]*m[10]  - m[0]*m[6]*m[9]   - m[4]*m[1]*m[10] + m[4]*m[2]*m[9]  + m[8]*m[1]*m[6]   - m[8]*m[2]*m[5];

    float det = m[0]*inv[0] + m[1]*inv[4] + m[2]*inv[8] + m[3]*inv[12];
    float rdet = 1.0f / det;
#pragma unroll
    for (int i = 0; i < 16; ++i) inv[i] *= rdet;

#pragma unroll
    for (int r = 0; r < 4; ++r)
#pragma unroll
        for (int c = 0; c < 4; ++c) {
            float acc = 0.f;
#pragma unroll
            for (int k = 0; k < 4; ++k) acc += inv[r*4 + k] * poseA[k*4 + c];
            T[r*4 + c] = acc;
        }
}

// ---------- per-pixel table: {u_B, v_B, valid, 0} for every pixel ----------
__global__ __launch_bounds__(256) void table_kernel(
    const float* __restrict__ depthA, const float* __restrict__ depthB,
    const float* __restrict__ T, f32x4* __restrict__ table) {
    const int pix = blockIdx.x * blockDim.x + threadIdx.x;
    if (pix >= NPIX) return;
    const int u = pix % IMG_W;
    const int v = pix / IMG_W;
    const float t00 = T[0],  t01 = T[1],  t02 = T[2],  t03 = T[3];
    const float t10 = T[4],  t11 = T[5],  t12 = T[6],  t13 = T[7];
    const float t20 = T[8],  t21 = T[9],  t22 = T[10], t23 = T[11];

    const float z  = depthA[pix];
    const float dB = depthB[pix];
    const float x = ((float)u - CXc) * z / FXc;
    const float y = ((float)v - CYc) * z / FYc;
    const float pbx = t00*x + t01*y + t02*z + t03;
    const float pby = t10*x + t11*y + t12*z + t13;
    const float pbz = t20*x + t21*y + t22*z + t23;
    const float uB = FXc * pbx / pbz + CXc;
    const float vB = FYc * pby / pbz + CYc;
    const float uBi = truncf(uB);
    const float vBi = truncf(vB);
    const bool valid = (z > 0.f)
        & (uBi > 0.f) & (uBi < (float)IMG_W)
        & (vBi > 0.f) & (vBi < (float)IMG_H)
        & (dB > 0.f) & (dB >= pbz - DEPTH_MARGIN);
    f32x4 t;
    t.x = uB; t.y = vB; t.z = valid ? 1.f : 0.f; t.w = 0.f;
    table[pix] = t;
}

// ---------- main kernel: 8 samples / thread, one float4 gather each ----------
__global__ __launch_bounds__(256) void sample_kernel(
    const int* __restrict__ uA, const int* __restrict__ vA,
    const f32x4* __restrict__ table, float* __restrict__ out,
    int n8, int n) {
    const int i = blockIdx.x * blockDim.x + threadIdx.x;
    if (i < n8) {
        // streaming index loads — non-temporal to keep L2 for the table
        const i32x4* u4p = (const i32x4*)uA;
        const i32x4* v4p = (const i32x4*)vA;
        i32x4 u0 = __builtin_nontemporal_load(&u4p[2*i]);
        i32x4 u1 = __builtin_nontemporal_load(&u4p[2*i + 1]);
        i32x4 v0 = __builtin_nontemporal_load(&v4p[2*i]);
        i32x4 v1 = __builtin_nontemporal_load(&v4p[2*i + 1]);
        int pix[8];
        pix[0] = v0.x * IMG_W + u0.x;  pix[1] = v0.y * IMG_W + u0.y;
        pix[2] = v0.z * IMG_W + u0.z;  pix[3] = v0.w * IMG_W + u0.w;
        pix[4] = v1.x * IMG_W + u1.x;  pix[5] = v1.y * IMG_W + u1.y;
        pix[6] = v1.z * IMG_W + u1.z;  pix[7] = v1.w * IMG_W + u1.w;
        f32x4 g[8];
#pragma unroll
        for (int j = 0; j < 8; ++j) g[j] = table[pix[j]];   // L2-resident gather
        // pack 8 × (uB,vB,valid) -> 24 floats -> 6 float4, non-temporal stores
        float o[24];
#pragma unroll
        for (int j = 0; j < 8; ++j) {
            o[j*3 + 0] = g[j].x;
            o[j*3 + 1] = g[j].y;
            o[j*3 + 2] = g[j].z;
        }
        f32x4* ob = (f32x4*)(out + (size_t)i * 24);
#pragma unroll
        for (int q = 0; q < 6; ++q) {
            f32x4 w;
            w.x = o[q*4+0]; w.y = o[q*4+1]; w.z = o[q*4+2]; w.w = o[q*4+3];
            __builtin_nontemporal_store(w, &ob[q]);
        }
    }
    // tail (n not divisible by 8)
    const int tail0 = n8 * 8;
    const int gtid = blockIdx.x * blockDim.x + threadIdx.x;
    const int stride = gridDim.x * blockDim.x;
    for (int s = tail0 + gtid; s < n; s += stride) {
        const int pixs = vA[s] * IMG_W + uA[s];
        f32x4 g = table[pixs];
        out[(size_t)s*3 + 0] = g.x;
        out[(size_t)s*3 + 1] = g.y;
        out[(size_t)s*3 + 2] = g.z;
    }
}

// ---------- fallback (ws too small): previous direct kernel ----------
__global__ __launch_bounds__(256) void corr_kernel(
    const float* __restrict__ depthA, const float* __restrict__ depthB,
    const int*   __restrict__ uA,     const int*   __restrict__ vA,
    const float* __restrict__ T,      float* __restrict__ out,
    int n4, int n) {
    const float t00 = T[0],  t01 = T[1],  t02 = T[2],  t03 = T[3];
    const float t10 = T[4],  t11 = T[5],  t12 = T[6],  t13 = T[7];
    const float t20 = T[8],  t21 = T[9],  t22 = T[10], t23 = T[11];
    const int stride = gridDim.x * blockDim.x;
    for (int i = blockIdx.x * blockDim.x + threadIdx.x; i < n4; i += stride) {
        int4 u4 = ((const int4*)uA)[i];
        int4 v4 = ((const int4*)vA)[i];
        float4 o[3];
        float* op = (float*)o;
        const int us[4] = {u4.x, u4.y, u4.z, u4.w};
        const int vs[4] = {v4.x, v4.y, v4.z, v4.w};
#pragma unroll
        for (int j = 0; j < 4; ++j) {
            const int u = us[j], v = vs[j];
            const int pix = v * IMG_W + u;
            const float z  = depthA[pix];
            const float dB = depthB[pix];
            const float x = ((float)u - CXc) * z / FXc;
            const float y = ((float)v - CYc) * z / FYc;
            const float pbx = t00*x + t01*y + t02*z + t03;
            const float pby = t10*x + t11*y + t12*z + t13;
            const float pbz = t20*x + t21*y + t22*z + t23;
            const float uB = FXc * pbx / pbz + CXc;
            const float vB = FYc * pby / pbz + CYc;
            const float uBi = truncf(uB);
            const float vBi = truncf(vB);
            const bool valid = (z > 0.f)
                & (uBi > 0.f) & (uBi < (float)IMG_W)
                & (vBi > 0.f) & (vBi < (float)IMG_H)
                & (dB > 0.f) & (dB >= pbz - DEPTH_MARGIN);
            op[j*3 + 0] = uB;
            op[j*3 + 1] = vB;
            op[j*3 + 2] = valid ? 1.f : 0.f;
        }
        float4* ob = (float4*)out + (size_t)i * 3;
        ob[0] = o[0]; ob[1] = o[1]; ob[2] = o[2];
    }
    const int tail0 = n4 * 4;
    const int gtid = blockIdx.x * blockDim.x + threadIdx.x;
    for (int s = tail0 + gtid; s < n; s += stride) {
        const int u = uA[s], v = vA[s];
        const int pix = v * IMG_W + u;
        const float z  = depthA[pix];
        const float dB = depthB[pix];
        const float x = ((float)u - CXc) * z / FXc;
        const float y = ((float)v - CYc) * z / FYc;
        const float pbx = t00*x + t01*y + t02*z + t03;
        const float pby = t10*x + t11*y + t12*z + t13;
        const float pbz = t20*x + t21*y + t22*z + t23;
        const float uB = FXc * pbx / pbz + CXc;
        const float vB = FYc * pby / pbz + CYc;
        const float uBi = truncf(uB);
        const float vBi = truncf(vB);
        const bool valid = (z > 0.f)
            & (uBi > 0.f) & (uBi < (float)IMG_W)
            & (vBi > 0.f) & (vBi < (float)IMG_H)
            & (dB > 0.f) & (dB >= pbz - DEPTH_MARGIN);
        out[(size_t)s*3 + 0] = uB;
        out[(size_t)s*3 + 1] = vB;
        out[(size_t)s*3 + 2] = valid ? 1.f : 0.f;
    }
}

extern "C" void kernel_launch(void* const* d_in, const int* in_sizes, int n_in,
                              void* d_out, int out_size, void* d_ws, size_t ws_size,
                              hipStream_t stream) {
    // inputs: 0 in_A(unused) 1 depth_A 2 pose_A 3 in_B(unused) 4 depth_B 5 pose_B 6 u_A 7 v_A
    const float* depthA = (const float*)d_in[1];
    const float* poseA  = (const float*)d_in[2];
    const float* depthB = (const float*)d_in[4];
    const float* poseB  = (const float*)d_in[5];
    const int*   uA     = (const int*)d_in[6];
    const int*   vA     = (const int*)d_in[7];
    float* out = (float*)d_out;

    float* T = (float*)d_ws;                         // 64 B
    const size_t table_off = 256;                    // 16B-aligned
    const size_t table_bytes = (size_t)NPIX * 16;

    const int n  = in_sizes[6];

    compute_T_kernel<<<1, 64, 0, stream>>>(poseA, poseB, T);

    if (ws_size >= table_off + table_bytes) {
        f32x4* table = (f32x4*)((char*)d_ws + table_off);
        table_kernel<<<(NPIX + 255) / 256, 256, 0, stream>>>(depthA, depthB, T, table);
        const int n8 = n / 8;
        int blocks = (n8 + 255) / 256;
        if (blocks < 1) blocks = 1;
        sample_kernel<<<blocks, 256, 0, stream>>>(uA, vA, table, out, n8, n);
    } else {
        const int n4 = n / 4;
        int blocks = (n4 + 255) / 256;
        if (blocks > 2048) blocks = 2048;
        if (blocks < 1) blocks = 1;
        corr_kernel<<<blocks, 256, 0, stream>>>(depthA, depthB, uA, vA, T, out, n4, n);
    }
}

// Round 3
// 124.126 us; speedup vs baseline: 1.0584x; 1.0584x over previous
//
#include <hip/hip_runtime.h>

#define FXc 384.996f
#define FYc 384.996f
#define CXc 325.85f
#define CYc 237.646f
#define DEPTH_MARGIN 0.003f
#define IMG_H 480
#define IMG_W 640
#define NPIX (IMG_H * IMG_W)

typedef int   i32x4 __attribute__((ext_vector_type(4)));
typedef float f32x2 __attribute__((ext_vector_type(2)));
typedef float f32x4 __attribute__((ext_vector_type(4)));

// ---------- tiny kernel: T = inv(pose_B) @ pose_A ----------
__global__ void compute_T_kernel(const float* __restrict__ poseA,
                                 const float* __restrict__ poseB,
                                 float* __restrict__ T) {
    if (threadIdx.x != 0 || blockIdx.x != 0) return;
    float m[16], inv[16];
#pragma unroll
    for (int i = 0; i < 16; ++i) m[i] = poseB[i];

    inv[0]  =  m[5]*m[10]*m[15] - m[5]*m[11]*m[14] - m[9]*m[6]*m[15] + m[9]*m[7]*m[14] + m[13]*m[6]*m[11] - m[13]*m[7]*m[10];
    inv[4]  = -m[4]*m[10]*m[15] + m[4]*m[11]*m[14] + m[8]*m[6]*m[15] - m[8]*m[7]*m[14] - m[12]*m[6]*m[11] + m[12]*m[7]*m[10];
    inv[8]  =  m[4]*m[9]*m[15]  - m[4]*m[11]*m[13] - m[8]*m[5]*m[15] + m[8]*m[7]*m[13] + m[12]*m[5]*m[11] - m[12]*m[7]*m[9];
    inv[12] = -m[4]*m[9]*m[14]  + m[4]*m[10]*m[13] + m[8]*m[5]*m[14] - m[8]*m[6]*m[13] - m[12]*m[5]*m[10] + m[12]*m[6]*m[9];
    inv[1]  = -m[1]*m[10]*m[15] + m[1]*m[11]*m[14] + m[9]*m[2]*m[15] - m[9]*m[3]*m[14] - m[13]*m[2]*m[11] + m[13]*m[3]*m[10];
    inv[5]  =  m[0]*m[10]*m[15] - m[0]*m[11]*m[14] - m[8]*m[2]*m[15] + m[8]*m[3]*m[14] + m[12]*m[2]*m[11] - m[12]*m[3]*m[10];
    inv[9]  = -m[0]*m[9]*m[15]  + m[0]*m[11]*m[13] + m[8]*m[1]*m[15] - m[8]*m[3]*m[13] - m[12]*m[1]*m[11] + m[12]*m[3]*m[9];
    inv[13] =  m[0]*m[9]*m[14]  - m[0]*m[10]*m[13] - m[8]*m[1]*m[14] + m[8]*m[2]*m[13] + m[12]*m[1]*m[10] - m[12]*m[2]*m[9];
    inv[2]  =  m[1]*m[6]*m[15]  - m[1]*m[7]*m[14]  - m[5]*m[2]*m[15] + m[5]*m[3]*m[14] + m[13]*m[2]*m[7]  - m[13]*m[3]*m[6];
    inv[6]  = -m[0]*m[6]*m[15]  + m[0]*m[7]*m[14]  + m[4]*m[2]*m[15] - m[4]*m[3]*m[14] - m[12]*m[2]*m[7]  + m[12]*m[3]*m[6];
    inv[10] =  m[0]*m[5]*m[15]  - m[0]*m[7]*m[13]  - m[4]*m[1]*m[15] + m[4]*m[3]*m[13] + m[12]*m[1]*m[7]  - m[12]*m[3]*m[5];
    inv[14] = -m[0]*m[5]*m[14]  + m[0]*m[6]*m[13]  + m[4]*m[1]*m[14] - m[4]*m[2]*m[13] - m[12]*m[1]*m[6]  + m[12]*m[2]*m[5];
    inv[3]  = -m[1]*m[6]*m[11]  + m[1]*m[7]*m[10]  + m[5]*m[2]*m[11] - m[5]*m[3]*m[10] - m[9]*m[2]*m[7]   + m[9]*m[3]*m[6];
    inv[7]  =  m[0]*m[6]*m[11]  - m[0]*m[7]*m[10]  - m[4]*m[2]*m[11] + m[4]*m[3]*m[10] + m[8]*m[2]*m[7]   - m[8]*m[3]*m[6];
    inv[11] = -m[0]*m[5]*m[11]  + m[0]*m[7]*m[9]   + m[4]*m[1]*m[11] - m[4]*m[3]*m[9]  - m[8]*m[1]*m[7]   + m[8]*m[3]*m[5];
    inv[15] =  m[0]*m[5]*m[10]  - m[0]*m[6]*m[9]   - m[4]*m[1]*m[10] + m[4]*m[2]*m[9]  + m[8]*m[1]*m[6]   - m[8]*m[2]*m[5];

    float det = m[0]*inv[0] + m[1]*inv[4] + m[2]*inv[8] + m[3]*inv[12];
    float rdet = 1.0f / det;
#pragma unroll
    for (int i = 0; i < 16; ++i) inv[i] *= rdet;

#pragma unroll
    for (int r = 0; r < 4; ++r)
#pragma unroll
        for (int c = 0; c < 4; ++c) {
            float acc = 0.f;
#pragma unroll
            for (int k = 0; k < 4; ++k) acc += inv[r*4 + k] * poseA[k*4 + c];
            T[r*4 + c] = acc;
        }
}

// ---------- pack kernel: zip[pix] = {depthA[pix], depthB[pix]} ----------
// 2.4 MB result fits in a 4 MB per-XCD L2 -> main-pass gathers are L2 hits.
__global__ __launch_bounds__(256) void pack_kernel(
    const float* __restrict__ dA, const float* __restrict__ dB,
    f32x2* __restrict__ zip) {
    const int i = blockIdx.x * blockDim.x + threadIdx.x;  // 4 pixels / thread
    if (i >= NPIX / 4) return;
    f32x4 a = ((const f32x4*)dA)[i];
    f32x4 b = ((const f32x4*)dB)[i];
    f32x4 lo, hi;
    lo.x = a.x; lo.y = b.x; lo.z = a.y; lo.w = b.y;
    hi.x = a.z; hi.y = b.z; hi.z = a.w; hi.w = b.w;
    ((f32x4*)zip)[2*i]     = lo;
    ((f32x4*)zip)[2*i + 1] = hi;
}

// ---------- main kernel: 8 samples / thread, one float2 gather each ----------
__global__ __launch_bounds__(256) void sample_kernel(
    const int* __restrict__ uA, const int* __restrict__ vA,
    const f32x2* __restrict__ zip, const float* __restrict__ T,
    float* __restrict__ out, int n8, int n) {
    const float t00 = T[0],  t01 = T[1],  t02 = T[2],  t03 = T[3];
    const float t10 = T[4],  t11 = T[5],  t12 = T[6],  t13 = T[7];
    const float t20 = T[8],  t21 = T[9],  t22 = T[10], t23 = T[11];

    const int i = blockIdx.x * blockDim.x + threadIdx.x;
    if (i < n8) {
        const i32x4* u4p = (const i32x4*)uA;
        const i32x4* v4p = (const i32x4*)vA;
        // streaming, non-temporal: don't evict the zip table from L2
        i32x4 u0 = __builtin_nontemporal_load(&u4p[2*i]);
        i32x4 u1 = __builtin_nontemporal_load(&u4p[2*i + 1]);
        i32x4 v0 = __builtin_nontemporal_load(&v4p[2*i]);
        i32x4 v1 = __builtin_nontemporal_load(&v4p[2*i + 1]);
        int u[8] = {u0.x, u0.y, u0.z, u0.w, u1.x, u1.y, u1.z, u1.w};
        int v[8] = {v0.x, v0.y, v0.z, v0.w, v1.x, v1.y, v1.z, v1.w};
        // issue all 8 gathers before any use -> 8 loads in flight
        f32x2 g[8];
#pragma unroll
        for (int j = 0; j < 8; ++j) g[j] = zip[v[j] * IMG_W + u[j]];

        float o[24];
#pragma unroll
        for (int j = 0; j < 8; ++j) {
            const float z  = g[j].x;
            const float dB = g[j].y;
            const float x = ((float)u[j] - CXc) * z / FXc;
            const float y = ((float)v[j] - CYc) * z / FYc;
            const float pbx = t00*x + t01*y + t02*z + t03;
            const float pby = t10*x + t11*y + t12*z + t13;
            const float pbz = t20*x + t21*y + t22*z + t23;
            const float uB = FXc * pbx / pbz + CXc;
            const float vB = FYc * pby / pbz + CYc;
            const float uBi = truncf(uB);
            const float vBi = truncf(vB);
            const bool valid = (z > 0.f)
                & (uBi > 0.f) & (uBi < (float)IMG_W)
                & (vBi > 0.f) & (vBi < (float)IMG_H)
                & (dB > 0.f) & (dB >= pbz - DEPTH_MARGIN);
            o[j*3 + 0] = uB;
            o[j*3 + 1] = vB;
            o[j*3 + 2] = valid ? 1.f : 0.f;
        }
        f32x4* ob = (f32x4*)(out + (size_t)i * 24);
#pragma unroll
        for (int q = 0; q < 6; ++q) {
            f32x4 w;
            w.x = o[q*4+0]; w.y = o[q*4+1]; w.z = o[q*4+2]; w.w = o[q*4+3];
            __builtin_nontemporal_store(w, &ob[q]);
        }
    }
    // tail (n not divisible by 8)
    const int tail0 = n8 * 8;
    const int gtid = blockIdx.x * blockDim.x + threadIdx.x;
    const int stride = gridDim.x * blockDim.x;
    for (int s = tail0 + gtid; s < n; s += stride) {
        const int uu = uA[s], vv = vA[s];
        f32x2 g = zip[vv * IMG_W + uu];
        const float z  = g.x;
        const float dB = g.y;
        const float x = ((float)uu - CXc) * z / FXc;
        const float y = ((float)vv - CYc) * z / FYc;
        const float pbx = t00*x + t01*y + t02*z + t03;
        const float pby = t10*x + t11*y + t12*z + t13;
        const float pbz = t20*x + t21*y + t22*z + t23;
        const float uB = FXc * pbx / pbz + CXc;
        const float vB = FYc * pby / pbz + CYc;
        const float uBi = truncf(uB);
        const float vBi = truncf(vB);
        const bool valid = (z > 0.f)
            & (uBi > 0.f) & (uBi < (float)IMG_W)
            & (vBi > 0.f) & (vBi < (float)IMG_H)
            & (dB > 0.f) & (dB >= pbz - DEPTH_MARGIN);
        out[(size_t)s*3 + 0] = uB;
        out[(size_t)s*3 + 1] = vB;
        out[(size_t)s*3 + 2] = valid ? 1.f : 0.f;
    }
}

extern "C" void kernel_launch(void* const* d_in, const int* in_sizes, int n_in,
                              void* d_out, int out_size, void* d_ws, size_t ws_size,
                              hipStream_t stream) {
    // inputs: 0 in_A(unused) 1 depth_A 2 pose_A 3 in_B(unused) 4 depth_B 5 pose_B 6 u_A 7 v_A
    const float* depthA = (const float*)d_in[1];
    const float* poseA  = (const float*)d_in[2];
    const float* depthB = (const float*)d_in[4];
    const float* poseB  = (const float*)d_in[5];
    const int*   uA     = (const int*)d_in[6];
    const int*   vA     = (const int*)d_in[7];
    float* out = (float*)d_out;

    float* T = (float*)d_ws;                          // 64 B
    const size_t zip_off = 256;                       // 16B-aligned
    f32x2* zip = (f32x2*)((char*)d_ws + zip_off);     // 2.4 MB

    const int n  = in_sizes[6];
    const int n8 = n / 8;

    compute_T_kernel<<<1, 64, 0, stream>>>(poseA, poseB, T);
    pack_kernel<<<(NPIX/4 + 255) / 256, 256, 0, stream>>>(depthA, depthB, zip);

    int blocks = (n8 + 255) / 256;
    if (blocks < 1) blocks = 1;
    sample_kernel<<<blocks, 256, 0, stream>>>(uA, vA, zip, T, out, n8, n);
}

// Round 4
// 79.212 us; speedup vs baseline: 1.6585x; 1.5670x over previous
//
#include <hip/hip_runtime.h>

#define FXc 384.996f
#define FYc 384.996f
#define CXc 325.85f
#define CYc 237.646f
#define DEPTH_MARGIN 0.003f
#define IMG_H 480
#define IMG_W 640
#define NPIX (IMG_H * IMG_W)

#define SPT 8                 // samples per thread
#define TPB 256               // threads per block
#define SPB (SPT * TPB)       // samples per block = 2048

typedef int   i32x4 __attribute__((ext_vector_type(4)));
typedef float f32x4 __attribute__((ext_vector_type(4)));

// ---------- tiny kernel: T = inv(pose_B) @ pose_A ----------
__global__ void compute_T_kernel(const float* __restrict__ poseA,
                                 const float* __restrict__ poseB,
                                 float* __restrict__ T) {
    if (threadIdx.x != 0 || blockIdx.x != 0) return;
    float m[16], inv[16];
#pragma unroll
    for (int i = 0; i < 16; ++i) m[i] = poseB[i];

    inv[0]  =  m[5]*m[10]*m[15] - m[5]*m[11]*m[14] - m[9]*m[6]*m[15] + m[9]*m[7]*m[14] + m[13]*m[6]*m[11] - m[13]*m[7]*m[10];
    inv[4]  = -m[4]*m[10]*m[15] + m[4]*m[11]*m[14] + m[8]*m[6]*m[15] - m[8]*m[7]*m[14] - m[12]*m[6]*m[11] + m[12]*m[7]*m[10];
    inv[8]  =  m[4]*m[9]*m[15]  - m[4]*m[11]*m[13] - m[8]*m[5]*m[15] + m[8]*m[7]*m[13] + m[12]*m[5]*m[11] - m[12]*m[7]*m[9];
    inv[12] = -m[4]*m[9]*m[14]  + m[4]*m[10]*m[13] + m[8]*m[5]*m[14] - m[8]*m[6]*m[13] - m[12]*m[5]*m[10] + m[12]*m[6]*m[9];
    inv[1]  = -m[1]*m[10]*m[15] + m[1]*m[11]*m[14] + m[9]*m[2]*m[15] - m[9]*m[3]*m[14] - m[13]*m[2]*m[11] + m[13]*m[3]*m[10];
    inv[5]  =  m[0]*m[10]*m[15] - m[0]*m[11]*m[14] - m[8]*m[2]*m[15] + m[8]*m[3]*m[14] + m[12]*m[2]*m[11] - m[12]*m[3]*m[10];
    inv[9]  = -m[0]*m[9]*m[15]  + m[0]*m[11]*m[13] + m[8]*m[1]*m[15] - m[8]*m[3]*m[13] - m[12]*m[1]*m[11] + m[12]*m[3]*m[9];
    inv[13] =  m[0]*m[9]*m[14]  - m[0]*m[10]*m[13] - m[8]*m[1]*m[14] + m[8]*m[2]*m[13] + m[12]*m[1]*m[10] - m[12]*m[2]*m[9];
    inv[2]  =  m[1]*m[6]*m[15]  - m[1]*m[7]*m[14]  - m[5]*m[2]*m[15] + m[5]*m[3]*m[14] + m[13]*m[2]*m[7]  - m[13]*m[3]*m[6];
    inv[6]  = -m[0]*m[6]*m[15]  + m[0]*m[7]*m[14]  + m[4]*m[2]*m[15] - m[4]*m[3]*m[14] - m[12]*m[2]*m[7]  + m[12]*m[3]*m[6];
    inv[10] =  m[0]*m[5]*m[15]  - m[0]*m[7]*m[13]  - m[4]*m[1]*m[15] + m[4]*m[3]*m[13] + m[12]*m[1]*m[7]  - m[12]*m[3]*m[5];
    inv[14] = -m[0]*m[5]*m[14]  + m[0]*m[6]*m[13]  + m[4]*m[1]*m[14] - m[4]*m[2]*m[13] - m[12]*m[1]*m[6]  + m[12]*m[2]*m[5];
    inv[3]  = -m[1]*m[6]*m[11]  + m[1]*m[7]*m[10]  + m[5]*m[2]*m[11] - m[5]*m[3]*m[10] - m[9]*m[2]*m[7]   + m[9]*m[3]*m[6];
    inv[7]  =  m[0]*m[6]*m[11]  - m[0]*m[7]*m[10]  - m[4]*m[2]*m[11] + m[4]*m[3]*m[10] + m[8]*m[2]*m[7]   - m[8]*m[3]*m[6];
    inv[11] = -m[0]*m[5]*m[11]  + m[0]*m[7]*m[9]   + m[4]*m[1]*m[11] - m[4]*m[3]*m[9]  - m[8]*m[1]*m[7]   + m[8]*m[3]*m[5];
    inv[15] =  m[0]*m[5]*m[10]  - m[0]*m[6]*m[9]   - m[4]*m[1]*m[10] + m[4]*m[2]*m[9]  + m[8]*m[1]*m[6]   - m[8]*m[2]*m[5];

    float det = m[0]*inv[0] + m[1]*inv[4] + m[2]*inv[8] + m[3]*inv[12];
    float rdet = 1.0f / det;
#pragma unroll
    for (int i = 0; i < 16; ++i) inv[i] *= rdet;

#pragma unroll
    for (int r = 0; r < 4; ++r)
#pragma unroll
        for (int c = 0; c < 4; ++c) {
            float acc = 0.f;
#pragma unroll
            for (int k = 0; k < 4; ++k) acc += inv[r*4 + k] * poseA[k*4 + c];
            T[r*4 + c] = acc;
        }
}

// ---------- per-pixel precompute: 8B entry {uB fix16.16 | valid, vB fix16.16} ----------
// 2.4 MB -> stays resident in a 4 MB per-XCD L2 under LRU (gathers keep it hot).
__global__ __launch_bounds__(256) void table_kernel(
    const float* __restrict__ depthA, const float* __restrict__ depthB,
    const float* __restrict__ T, int2* __restrict__ tbl) {
    const int pix = blockIdx.x * blockDim.x + threadIdx.x;
    if (pix >= NPIX) return;
    const int u = pix % IMG_W;
    const int v = pix / IMG_W;
    const float t00 = T[0],  t01 = T[1],  t02 = T[2],  t03 = T[3];
    const float t10 = T[4],  t11 = T[5],  t12 = T[6],  t13 = T[7];
    const float t20 = T[8],  t21 = T[9],  t22 = T[10], t23 = T[11];

    const float z  = depthA[pix];
    const float dB = depthB[pix];
    const float x = ((float)u - CXc) * z / FXc;
    const float y = ((float)v - CYc) * z / FYc;
    const float pbx = t00*x + t01*y + t02*z + t03;
    const float pby = t10*x + t11*y + t12*z + t13;
    const float pbz = t20*x + t21*y + t22*z + t23;
    const float uB = FXc * pbx / pbz + CXc;
    const float vB = FYc * pby / pbz + CYc;
    const float uBi = truncf(uB);
    const float vBi = truncf(vB);
    const bool valid = (z > 0.f)
        & (uBi > 0.f) & (uBi < (float)IMG_W)
        & (vBi > 0.f) & (vBi < (float)IMG_H)
        & (dB > 0.f) & (dB >= pbz - DEPTH_MARGIN);
    // 16.16 fixed point; geometry bounds |uB|,|vB| < ~1000, clamp is pure safety
    const float uc = fminf(fmaxf(uB, -29000.f), 29000.f);
    const float vc = fminf(fmaxf(vB, -29000.f), 29000.f);
    int iu = (int)__builtin_rintf(uc * 65536.f);
    int iv = (int)__builtin_rintf(vc * 65536.f);
    iu = (iu & ~1) | (valid ? 1 : 0);      // steal bit 0 for the valid flag
    int2 e; e.x = iu; e.y = iv;
    tbl[pix] = e;
}

// ---------- main kernel: 8 samples/thread, 1×8B gather, LDS-transposed stores ----------
__global__ __launch_bounds__(256) void sample_kernel(
    const int* __restrict__ uA, const int* __restrict__ vA,
    const int2* __restrict__ tbl, float* __restrict__ out, int n) {
    __shared__ float4 lds[SPB];            // 32 KB -> 5 blocks/CU
    const int t = threadIdx.x;
    const long long base = (long long)blockIdx.x * SPB;
    const float inv64k = 1.52587890625e-05f;   // 1/65536

    if (base + SPB <= (long long)n) {
        const int gi = blockIdx.x * TPB + t;   // index in units of 8 samples
        const i32x4* u4p = (const i32x4*)uA;
        const i32x4* v4p = (const i32x4*)vA;
        // streaming index loads: non-temporal (no L2 allocate -> keep tbl hot)
        i32x4 u0 = __builtin_nontemporal_load(&u4p[2*gi]);
        i32x4 u1 = __builtin_nontemporal_load(&u4p[2*gi + 1]);
        i32x4 v0 = __builtin_nontemporal_load(&v4p[2*gi]);
        i32x4 v1 = __builtin_nontemporal_load(&v4p[2*gi + 1]);
        const int uu[8] = {u0.x, u0.y, u0.z, u0.w, u1.x, u1.y, u1.z, u1.w};
        const int vv[8] = {v0.x, v0.y, v0.z, v0.w, v1.x, v1.y, v1.z, v1.w};
        int2 g[8];
#pragma unroll
        for (int j = 0; j < 8; ++j) g[j] = tbl[vv[j] * IMG_W + uu[j]];  // L2-hit gathers

        // unpack + deposit to LDS (XOR swizzle: bijective, both sides use same formula)
#pragma unroll
        for (int j = 0; j < 8; ++j) {
            const int f = t * SPT + j;
            const int slot = f ^ ((f >> 4) & 7);
            float4 e;
            e.x = (float)(g[j].x & ~1) * inv64k;
            e.y = (float)(g[j].y)      * inv64k;
            e.z = (float)(g[j].x & 1);
            e.w = 0.f;
            lds[slot] = e;
        }
        __syncthreads();

        // coalesced write-out: lane-contiguous 12B (float3) stores
        float3* ob = (float3*)(out + base * 3);
#pragma unroll
        for (int m = 0; m < SPT; ++m) {
            const int f = m * TPB + t;
            const int slot = f ^ ((f >> 4) & 7);
            float4 e = lds[slot];
            float3 w; w.x = e.x; w.y = e.y; w.z = e.z;
            ob[f] = w;
        }
    } else {
        // partial tail block: simple per-sample path
        for (long long s = base + t; s < (long long)n; s += TPB) {
            int2 gg = tbl[vA[s] * IMG_W + uA[s]];
            out[s*3 + 0] = (float)(gg.x & ~1) * inv64k;
            out[s*3 + 1] = (float)(gg.y)      * inv64k;
            out[s*3 + 2] = (float)(gg.x & 1);
        }
    }
}

extern "C" void kernel_launch(void* const* d_in, const int* in_sizes, int n_in,
                              void* d_out, int out_size, void* d_ws, size_t ws_size,
                              hipStream_t stream) {
    // inputs: 0 in_A(unused) 1 depth_A 2 pose_A 3 in_B(unused) 4 depth_B 5 pose_B 6 u_A 7 v_A
    const float* depthA = (const float*)d_in[1];
    const float* poseA  = (const float*)d_in[2];
    const float* depthB = (const float*)d_in[4];
    const float* poseB  = (const float*)d_in[5];
    const int*   uA     = (const int*)d_in[6];
    const int*   vA     = (const int*)d_in[7];
    float* out = (float*)d_out;

    float* T = (float*)d_ws;                          // 64 B
    int2* tbl = (int2*)((char*)d_ws + 256);           // 2.4 MB, 16B-aligned

    const int n = in_sizes[6];

    compute_T_kernel<<<1, 64, 0, stream>>>(poseA, poseB, T);
    table_kernel<<<(NPIX + 255) / 256, 256, 0, stream>>>(depthA, depthB, T, tbl);

    const int blocks = (int)(((long long)n + SPB - 1) / SPB);
    sample_kernel<<<blocks, TPB, 0, stream>>>(uA, vA, tbl, out, n);
}

// Round 5
// 75.618 us; speedup vs baseline: 1.7373x; 1.0475x over previous
//
#include <hip/hip_runtime.h>

#define FXc 384.996f
#define FYc 384.996f
#define CXc 325.85f
#define CYc 237.646f
#define DEPTH_MARGIN 0.003f
#define IMG_H 480
#define IMG_W 640
#define NPIX (IMG_H * IMG_W)

#define SPT 8                 // samples per thread
#define TPB 256               // threads per block
#define SPB (SPT * TPB)       // samples per block = 2048

typedef int   i32x4 __attribute__((ext_vector_type(4)));
typedef float f32x4 __attribute__((ext_vector_type(4)));

// ---------- device helper: T = inv(pose_B) @ pose_A (rows 0..2) ----------
__device__ __forceinline__ void make_T(const float* __restrict__ poseA,
                                       const float* __restrict__ poseB,
                                       float* __restrict__ T /*12*/) {
    float m[16], inv[16];
#pragma unroll
    for (int i = 0; i < 16; ++i) m[i] = poseB[i];

    inv[0]  =  m[5]*m[10]*m[15] - m[5]*m[11]*m[14] - m[9]*m[6]*m[15] + m[9]*m[7]*m[14] + m[13]*m[6]*m[11] - m[13]*m[7]*m[10];
    inv[4]  = -m[4]*m[10]*m[15] + m[4]*m[11]*m[14] + m[8]*m[6]*m[15] - m[8]*m[7]*m[14] - m[12]*m[6]*m[11] + m[12]*m[7]*m[10];
    inv[8]  =  m[4]*m[9]*m[15]  - m[4]*m[11]*m[13] - m[8]*m[5]*m[15] + m[8]*m[7]*m[13] + m[12]*m[5]*m[11] - m[12]*m[7]*m[9];
    inv[12] = -m[4]*m[9]*m[14]  + m[4]*m[10]*m[13] + m[8]*m[5]*m[14] - m[8]*m[6]*m[13] - m[12]*m[5]*m[10] + m[12]*m[6]*m[9];
    inv[1]  = -m[1]*m[10]*m[15] + m[1]*m[11]*m[14] + m[9]*m[2]*m[15] - m[9]*m[3]*m[14] - m[13]*m[2]*m[11] + m[13]*m[3]*m[10];
    inv[5]  =  m[0]*m[10]*m[15] - m[0]*m[11]*m[14] - m[8]*m[2]*m[15] + m[8]*m[3]*m[14] + m[12]*m[2]*m[11] - m[12]*m[3]*m[10];
    inv[9]  = -m[0]*m[9]*m[15]  + m[0]*m[11]*m[13] + m[8]*m[1]*m[15] - m[8]*m[3]*m[13] - m[12]*m[1]*m[11] + m[12]*m[3]*m[9];
    inv[13] =  m[0]*m[9]*m[14]  - m[0]*m[10]*m[13] - m[8]*m[1]*m[14] + m[8]*m[2]*m[13] + m[12]*m[1]*m[10] - m[12]*m[2]*m[9];
    inv[2]  =  m[1]*m[6]*m[15]  - m[1]*m[7]*m[14]  - m[5]*m[2]*m[15] + m[5]*m[3]*m[14] + m[13]*m[2]*m[7]  - m[13]*m[3]*m[6];
    inv[6]  = -m[0]*m[6]*m[15]  + m[0]*m[7]*m[14]  + m[4]*m[2]*m[15] - m[4]*m[3]*m[14] - m[12]*m[2]*m[7]  + m[12]*m[3]*m[6];
    inv[10] =  m[0]*m[5]*m[15]  - m[0]*m[7]*m[13]  - m[4]*m[1]*m[15] + m[4]*m[3]*m[13] + m[12]*m[1]*m[7]  - m[12]*m[3]*m[5];
    inv[14] = -m[0]*m[5]*m[14]  + m[0]*m[6]*m[13]  + m[4]*m[1]*m[14] - m[4]*m[2]*m[13] - m[12]*m[1]*m[6]  + m[12]*m[2]*m[5];
    inv[3]  = -m[1]*m[6]*m[11]  + m[1]*m[7]*m[10]  + m[5]*m[2]*m[11] - m[5]*m[3]*m[10] - m[9]*m[2]*m[7]   + m[9]*m[3]*m[6];
    inv[7]  =  m[0]*m[6]*m[11]  - m[0]*m[7]*m[10]  - m[4]*m[2]*m[11] + m[4]*m[3]*m[10] + m[8]*m[2]*m[7]   - m[8]*m[3]*m[6];
    inv[11] = -m[0]*m[5]*m[11]  + m[0]*m[7]*m[9]   + m[4]*m[1]*m[11] - m[4]*m[3]*m[9]  - m[8]*m[1]*m[7]   + m[8]*m[3]*m[5];
    inv[15] =  m[0]*m[5]*m[10]  - m[0]*m[6]*m[9]   - m[4]*m[1]*m[10] + m[4]*m[2]*m[9]  + m[8]*m[1]*m[6]   - m[8]*m[2]*m[5];

    float det = m[0]*inv[0] + m[1]*inv[4] + m[2]*inv[8] + m[3]*inv[12];
    float rdet = 1.0f / det;
#pragma unroll
    for (int i = 0; i < 16; ++i) inv[i] *= rdet;

#pragma unroll
    for (int r = 0; r < 3; ++r)
#pragma unroll
        for (int c = 0; c < 4; ++c) {
            float acc = 0.f;
#pragma unroll
            for (int k = 0; k < 4; ++k) acc += inv[r*4 + k] * poseA[k*4 + c];
            T[r*4 + c] = acc;
        }
}

// ---------- per-pixel precompute: 8B entry {uB fix16.16 | valid, vB fix16.16} ----------
// 2.4 MB -> L2-resident (4 MB/XCD); T computed inline (registers, ~300 flops).
__global__ __launch_bounds__(256) void table_kernel(
    const float* __restrict__ depthA, const float* __restrict__ depthB,
    const float* __restrict__ poseA,  const float* __restrict__ poseB,
    int2* __restrict__ tbl) {
    const int pix = blockIdx.x * blockDim.x + threadIdx.x;
    if (pix >= NPIX) return;

    float T[12];
    make_T(poseA, poseB, T);

    const int u = pix % IMG_W;
    const int v = pix / IMG_W;
    const float z  = depthA[pix];
    const float dB = depthB[pix];
    const float x = ((float)u - CXc) * z / FXc;
    const float y = ((float)v - CYc) * z / FYc;
    const float pbx = T[0]*x + T[1]*y + T[2]*z  + T[3];
    const float pby = T[4]*x + T[5]*y + T[6]*z  + T[7];
    const float pbz = T[8]*x + T[9]*y + T[10]*z + T[11];
    const float uB = FXc * pbx / pbz + CXc;
    const float vB = FYc * pby / pbz + CYc;
    const float uBi = truncf(uB);
    const float vBi = truncf(vB);
    const bool valid = (z > 0.f)
        & (uBi > 0.f) & (uBi < (float)IMG_W)
        & (vBi > 0.f) & (vBi < (float)IMG_H)
        & (dB > 0.f) & (dB >= pbz - DEPTH_MARGIN);
    const float uc = fminf(fmaxf(uB, -29000.f), 29000.f);
    const float vc = fminf(fmaxf(vB, -29000.f), 29000.f);
    int iu = (int)__builtin_rintf(uc * 65536.f);
    int iv = (int)__builtin_rintf(vc * 65536.f);
    iu = (iu & ~1) | (valid ? 1 : 0);
    int2 e; e.x = iu; e.y = iv;
    tbl[pix] = e;
}

// ---------- main kernel: 8 samples/thread, 1×8B gather each, direct stores ----------
// No LDS, no barrier -> 8 blocks/CU (wave-limited), max memory-level parallelism.
__global__ __launch_bounds__(256, 8) void sample_kernel(
    const int* __restrict__ uA, const int* __restrict__ vA,
    const int2* __restrict__ tbl, float* __restrict__ out, int n) {
    const int t = threadIdx.x;
    const int i = blockIdx.x * TPB + t;          // unit of SPT samples
    const long long s0 = (long long)i * SPT;
    const float inv64k = 1.52587890625e-05f;     // 1/65536

    if (s0 + SPT <= (long long)n) {
        const i32x4* u4p = (const i32x4*)uA;
        const i32x4* v4p = (const i32x4*)vA;
        // cached loads: u/v fit L3 across replays
        i32x4 u0 = u4p[2*i];
        i32x4 u1 = u4p[2*i + 1];
        i32x4 v0 = v4p[2*i];
        i32x4 v1 = v4p[2*i + 1];
        const int uu[8] = {u0.x, u0.y, u0.z, u0.w, u1.x, u1.y, u1.z, u1.w};
        const int vv[8] = {v0.x, v0.y, v0.z, v0.w, v1.x, v1.y, v1.z, v1.w};
        // all 8 gathers issued before any use -> 8 in flight
        int2 g[8];
#pragma unroll
        for (int j = 0; j < 8; ++j) g[j] = tbl[vv[j] * IMG_W + uu[j]];

        float un[8], vn[8], fn[8];
#pragma unroll
        for (int j = 0; j < 8; ++j) {
            un[j] = (float)(g[j].x & ~1) * inv64k;
            vn[j] = (float)(g[j].y)      * inv64k;
            fn[j] = (float)(g[j].x & 1);
        }
        // 24 floats -> 6 contiguous float4 stores (96 B/thread, contiguous)
        f32x4* ob = (f32x4*)(out + s0 * 3);
        f32x4 w;
        w.x = un[0]; w.y = vn[0]; w.z = fn[0]; w.w = un[1]; ob[0] = w;
        w.x = vn[1]; w.y = fn[1]; w.z = un[2]; w.w = vn[2]; ob[1] = w;
        w.x = fn[2]; w.y = un[3]; w.z = vn[3]; w.w = fn[3]; ob[2] = w;
        w.x = un[4]; w.y = vn[4]; w.z = fn[4]; w.w = un[5]; ob[3] = w;
        w.x = vn[5]; w.y = fn[5]; w.z = un[6]; w.w = vn[6]; ob[4] = w;
        w.x = fn[6]; w.y = un[7]; w.z = vn[7]; w.w = fn[7]; ob[5] = w;
    } else {
        // partial tail: per-sample
        for (long long s = s0; s < (long long)n && s < s0 + SPT; ++s) {
            int2 gg = tbl[vA[s] * IMG_W + uA[s]];
            out[s*3 + 0] = (float)(gg.x & ~1) * inv64k;
            out[s*3 + 1] = (float)(gg.y)      * inv64k;
            out[s*3 + 2] = (float)(gg.x & 1);
        }
    }
}

extern "C" void kernel_launch(void* const* d_in, const int* in_sizes, int n_in,
                              void* d_out, int out_size, void* d_ws, size_t ws_size,
                              hipStream_t stream) {
    // inputs: 0 in_A(unused) 1 depth_A 2 pose_A 3 in_B(unused) 4 depth_B 5 pose_B 6 u_A 7 v_A
    const float* depthA = (const float*)d_in[1];
    const float* poseA  = (const float*)d_in[2];
    const float* depthB = (const float*)d_in[4];
    const float* poseB  = (const float*)d_in[5];
    const int*   uA     = (const int*)d_in[6];
    const int*   vA     = (const int*)d_in[7];
    float* out = (float*)d_out;

    int2* tbl = (int2*)d_ws;                       // 2.4 MB

    const int n = in_sizes[6];

    table_kernel<<<(NPIX + 255) / 256, 256, 0, stream>>>(depthA, depthB, poseA, poseB, tbl);

    const int blocks = (int)(((long long)n + SPB - 1) / SPB);
    sample_kernel<<<blocks, TPB, 0, stream>>>(uA, vA, tbl, out, n);
}